// Round 1
// baseline (577.724 us; speedup 1.0000x reference)
//
#include <hip/hip_runtime.h>
#include <hip/hip_bf16.h>
#include <stdint.h>

#define S_DIM 512
#define I_DIM 384
#define CMSA  64
#define CDIM  32
#define M_DIM (I_DIM*CDIM)   // 12288
#define P_DIM 128

typedef __attribute__((ext_vector_type(8))) short  s16x8;
typedef __attribute__((ext_vector_type(8))) __bf16 bf16x8;
typedef __attribute__((ext_vector_type(4))) float  f32x4;

static __device__ __forceinline__ unsigned short f2bf(float f) {
  union { float f; unsigned u; } v; v.f = f;
  unsigned r = v.u + 0x7FFFu + ((v.u >> 16) & 1u);
  return (unsigned short)(r >> 16);
}

static __device__ __forceinline__ void gload_lds16(const void* g, void* l) {
  __builtin_amdgcn_global_load_lds(
      (__attribute__((address_space(1))) void*)(g),
      (__attribute__((address_space(3))) void*)(l), 16, 0, 0);
}

// ---------------------------------------------------------------------------
// Kernel 1: LayerNorm + dual projection. Writes A,B bf16 in [m=i*32+c][s] layout
// (rows K-contiguous). 1/512 outer-product-mean scale folded into A.
// grid: (8 s-blocks, 384 i), block 256. Each 4-lane group owns one (s,i) row.
// ---------------------------------------------------------------------------
__global__ __launch_bounds__(256) void ln_proj_kernel(
    const float* __restrict__ msa, const float* __restrict__ gamma,
    const float* __restrict__ beta, const float* __restrict__ w_a,
    const float* __restrict__ w_b, unsigned short* __restrict__ Ag,
    unsigned short* __restrict__ Bg)
{
  __shared__ float wl[2][32][64];
  __shared__ float gb[2][64];
  __shared__ unsigned short atr[2][32][64];   // [a/b][c][s_local] for coalesced writeout

  const int tid = threadIdx.x;
  float* wflat = &wl[0][0][0];
  for (int t = tid; t < 2048; t += 256) { wflat[t] = w_a[t]; wflat[2048 + t] = w_b[t]; }
  if (tid < 64) { gb[0][tid] = gamma[tid]; gb[1][tid] = beta[tid]; }
  __syncthreads();

  const int q = tid & 3, sl = tid >> 2;
  const int s = blockIdx.x * 64 + sl;
  const int i = blockIdx.y;
  const float* row = msa + ((size_t)s * I_DIM + i) * CMSA + q * 16;

  float x[16];
  #pragma unroll
  for (int u = 0; u < 4; ++u) {
    float4 v = *(const float4*)(row + 4*u);
    x[4*u] = v.x; x[4*u+1] = v.y; x[4*u+2] = v.z; x[4*u+3] = v.w;
  }
  float sum = 0.f, sq = 0.f;
  #pragma unroll
  for (int j = 0; j < 16; ++j) { sum += x[j]; sq += x[j]*x[j]; }
  sum += __shfl_xor(sum, 1); sum += __shfl_xor(sum, 2);
  sq  += __shfl_xor(sq, 1);  sq  += __shfl_xor(sq, 2);
  const float mean = sum * (1.f/64.f);
  const float var  = sq  * (1.f/64.f) - mean*mean;
  const float rstd = rsqrtf(var + 1e-5f);
  float m[16];
  #pragma unroll
  for (int j = 0; j < 16; ++j)
    m[j] = (x[j] - mean) * rstd * gb[0][q*16+j] + gb[1][q*16+j];

  for (int c = 0; c < 32; ++c) {
    float pa = 0.f, pb = 0.f;
    #pragma unroll
    for (int u = 0; u < 4; ++u) {
      float4 wa = *(const float4*)&wl[0][c][q*16 + 4*u];
      float4 wb = *(const float4*)&wl[1][c][q*16 + 4*u];
      pa += m[4*u]*wa.x + m[4*u+1]*wa.y + m[4*u+2]*wa.z + m[4*u+3]*wa.w;
      pb += m[4*u]*wb.x + m[4*u+1]*wb.y + m[4*u+2]*wb.z + m[4*u+3]*wb.w;
    }
    pa += __shfl_xor(pa, 1); pa += __shfl_xor(pa, 2);
    pb += __shfl_xor(pb, 1); pb += __shfl_xor(pb, 2);
    if (q == 0) {
      atr[0][c][sl] = f2bf(pa * (1.f/512.f));  // fold 1/S into A
      atr[1][c][sl] = f2bf(pb);
    }
  }
  __syncthreads();
  // coalesced writeout: thread t -> c=t/8, 8 consecutive s (16B)
  const int c2 = tid >> 3, su = (tid & 7) * 8;
  const size_t gbase = ((size_t)i * CDIM + c2) * S_DIM + (size_t)blockIdx.x * 64 + su;
  *(s16x8*)(Ag + gbase) = *(const s16x8*)&atr[0][c2][su];
  *(s16x8*)(Bg + gbase) = *(const s16x8*)&atr[1][c2][su];
}

// ---------------------------------------------------------------------------
// Kernel 2: w_out fp32 -> bf16 [128][1024]
// ---------------------------------------------------------------------------
__global__ __launch_bounds__(256) void wconv_kernel(
    const float* __restrict__ w, unsigned short* __restrict__ wbf)
{
  const int idx = (blockIdx.x * 256 + threadIdx.x) * 4;   // 131072 total
  float4 v = *(const float4*)(w + idx);
  unsigned short o0 = f2bf(v.x), o1 = f2bf(v.y), o2 = f2bf(v.z), o3 = f2bf(v.w);
  unsigned long long packed = (unsigned long long)o0 | ((unsigned long long)o1 << 16)
                            | ((unsigned long long)o2 << 32) | ((unsigned long long)o3 << 48);
  *(unsigned long long*)(wbf + idx) = packed;
}

// ---------------------------------------------------------------------------
// Kernel 3: main fused GEMM.
//   o_tile(128x128, K=512)  then  z_tile(128p x 16pairs, K=1024) fused epilogue.
// 4 waves, each owns a 64x64 quadrant (4x4 fragments of 16x16x32 bf16 MFMA).
// LDS XOR-swizzle (slot ^= row&7) applied via pre-swizzled global source
// (global_load_lds writes linearly) and matching XOR on ds_read.
// ---------------------------------------------------------------------------
__global__ __launch_bounds__(256) void opm_gemm_kernel(
    const unsigned short* __restrict__ Ag, const unsigned short* __restrict__ Bg,
    const unsigned short* __restrict__ Wbf, const float* __restrict__ b_out,
    float* __restrict__ z)
{
  __shared__ __align__(16) unsigned char lds[32768];  // A:16K | B:16K, reused as O_lT 32K

  const int tid = threadIdx.x;
  const int l = tid & 63, w = tid >> 6;
  const int wr = w >> 1, wc = w & 1;
  const int bm = blockIdx.x, bn = blockIdx.y;

  f32x4 acc[4][4];
  #pragma unroll
  for (int a = 0; a < 4; ++a)
    #pragma unroll
    for (int b = 0; b < 4; ++b)
      acc[a][b] = (f32x4){0.f, 0.f, 0.f, 0.f};

  for (int kt = 0; kt < 8; ++kt) {
    // ---- stage 128x64 A and B tiles (16KB each) via global_load_lds x16 ----
    #pragma unroll
    for (int it = 0; it < 4; ++it) {
      const int off16 = (it*4 + w)*64 + l;        // 16B unit within tile (0..1023)
      const int r = off16 >> 3;                   // row 0..127
      const int srcslot = (off16 & 7) ^ (r & 7);  // inverse-swizzle the SOURCE
      const size_t ka = (size_t)kt*64 + srcslot*8;
      gload_lds16(Ag + ((size_t)(bm*128 + r))*S_DIM + ka, lds + off16*16);
      gload_lds16(Bg + ((size_t)(bn*128 + r))*S_DIM + ka, lds + 16384 + off16*16);
    }
    __syncthreads();
    // ---- compute: 2 k-steps of 32 ----
    #pragma unroll
    for (int ks = 0; ks < 2; ++ks) {
      bf16x8 af[4], bfv[4];
      const int kb = ks*64 + ((l >> 4) * 16);     // byte offset of this lane's k-slice
      #pragma unroll
      for (int mi = 0; mi < 4; ++mi) {
        const int rowA = wr*64 + mi*16 + (l & 15);
        int addrA = rowA*128 + kb; addrA ^= ((rowA & 7) << 4);
        af[mi] = *(const bf16x8*)(lds + addrA);
        const int rowB = wc*64 + mi*16 + (l & 15);
        int addrB = rowB*128 + kb; addrB ^= ((rowB & 7) << 4);
        bfv[mi] = *(const bf16x8*)(lds + 16384 + addrB);
      }
      #pragma unroll
      for (int mi = 0; mi < 4; ++mi)
        #pragma unroll
        for (int ni = 0; ni < 4; ++ni)
          acc[mi][ni] = __builtin_amdgcn_mfma_f32_16x16x32_bf16(
              af[mi], bfv[ni], acc[mi][ni], 0, 0, 0);
    }
    __syncthreads();
  }

  // ---- epilogue phase A: o-tile -> LDS as O_lT[pair][k], bf16, XOR-swizzled ----
  #pragma unroll
  for (int mi = 0; mi < 4; ++mi) {
    const int rowb = wr*64 + mi*16 + ((l >> 4) * 4);
    #pragma unroll
    for (int ni = 0; ni < 4; ++ni) {
      const int col = wc*64 + ni*16 + (l & 15);
      const int jloc = col >> 5, d = col & 31;
      #pragma unroll
      for (int r = 0; r < 4; ++r) {
        const int row = rowb + r;
        const int iloc = row >> 5, cc = row & 31;
        const int pair = iloc*4 + jloc;
        const int k = cc*32 + d;
        int addr = pair*2048 + k*2; addr ^= ((pair & 7) << 4);
        *(unsigned short*)(lds + addr) = f2bf(acc[mi][ni][r]);
      }
    }
  }
  __syncthreads();

  // ---- epilogue phase B: z[128p][16pairs] = Wbf(128x1024) @ O_lT^T ----
  f32x4 accz[2];
  accz[0] = (f32x4){0.f,0.f,0.f,0.f};
  accz[1] = (f32x4){0.f,0.f,0.f,0.f};
  for (int ks = 0; ks < 32; ++ks) {
    const int kb = ks*64 + ((l >> 4) * 16);
    int addr = (l & 15)*2048 + kb; addr ^= (((l & 15) & 7) << 4);
    const bf16x8 of = *(const bf16x8*)(lds + addr);
    #pragma unroll
    for (int t = 0; t < 2; ++t) {
      const int p = (w*2 + t)*16 + (l & 15);
      const bf16x8 wf = *(const bf16x8*)(Wbf + (size_t)p*1024 + ks*32 + (l >> 4)*8);
      accz[t] = __builtin_amdgcn_mfma_f32_16x16x32_bf16(wf, of, accz[t], 0, 0, 0);
    }
  }

  // ---- store z + b_out ----
  const int pair = l & 15;
  const int gi = bm*4 + (pair >> 2);
  const int gj = bn*4 + (pair & 3);
  const size_t zbase = ((size_t)gi * I_DIM + gj) * P_DIM;
  #pragma unroll
  for (int t = 0; t < 2; ++t) {
    const int p0 = (w*2 + t)*16 + ((l >> 4) * 4);
    #pragma unroll
    for (int r = 0; r < 4; ++r)
      z[zbase + p0 + r] = accz[t][r] + b_out[p0 + r];
  }
}

extern "C" void kernel_launch(void* const* d_in, const int* in_sizes, int n_in,
                              void* d_out, int out_size, void* d_ws, size_t ws_size,
                              hipStream_t stream) {
  const float* msa   = (const float*)d_in[0];
  const float* gamma = (const float*)d_in[1];
  const float* beta  = (const float*)d_in[2];
  const float* w_a   = (const float*)d_in[3];
  const float* w_b   = (const float*)d_in[4];
  const float* w_out = (const float*)d_in[5];
  const float* b_out = (const float*)d_in[6];
  float* z = (float*)d_out;

  unsigned short* Ag  = (unsigned short*)d_ws;                      // 12.6 MB
  unsigned short* Bg  = Ag + (size_t)M_DIM * S_DIM;                 // 12.6 MB
  unsigned short* Wbf = Bg + (size_t)M_DIM * S_DIM;                 // 256 KB

  hipLaunchKernelGGL(ln_proj_kernel, dim3(8, 384), dim3(256), 0, stream,
                     msa, gamma, beta, w_a, w_b, Ag, Bg);
  hipLaunchKernelGGL(wconv_kernel, dim3(128), dim3(256), 0, stream, w_out, Wbf);
  hipLaunchKernelGGL(opm_gemm_kernel, dim3(96, 96), dim3(256), 0, stream,
                     Ag, Bg, Wbf, b_out, z);
}

// Round 2
// 369.039 us; speedup vs baseline: 1.5655x; 1.5655x over previous
//
#include <hip/hip_runtime.h>
#include <hip/hip_bf16.h>
#include <stdint.h>

#define S_DIM 512
#define I_DIM 384
#define CMSA  64
#define CDIM  32
#define M_DIM (I_DIM*CDIM)   // 12288
#define P_DIM 128

typedef __attribute__((ext_vector_type(8))) short  s16x8;
typedef __attribute__((ext_vector_type(8))) __bf16 bf16x8;
typedef __attribute__((ext_vector_type(4))) float  f32x4;

static __device__ __forceinline__ unsigned short f2bf(float f) {
  union { float f; unsigned u; } v; v.f = f;
  unsigned r = v.u + 0x7FFFu + ((v.u >> 16) & 1u);
  return (unsigned short)(r >> 16);
}

static __device__ __forceinline__ void gload_lds16(const void* g, void* l) {
  __builtin_amdgcn_global_load_lds(
      (__attribute__((address_space(1))) void*)(g),
      (__attribute__((address_space(3))) void*)(l), 16, 0, 0);
}

// ---------------------------------------------------------------------------
// Kernel 1: LayerNorm + dual projection. A,B bf16 in [m=i*32+c][s] layout.
// 1/512 folded into A.
// ---------------------------------------------------------------------------
__global__ __launch_bounds__(256) void ln_proj_kernel(
    const float* __restrict__ msa, const float* __restrict__ gamma,
    const float* __restrict__ beta, const float* __restrict__ w_a,
    const float* __restrict__ w_b, unsigned short* __restrict__ Ag,
    unsigned short* __restrict__ Bg)
{
  __shared__ float wl[2][32][64];
  __shared__ float gb[2][64];
  __shared__ unsigned short atr[2][32][64];

  const int tid = threadIdx.x;
  float* wflat = &wl[0][0][0];
  for (int t = tid; t < 2048; t += 256) { wflat[t] = w_a[t]; wflat[2048 + t] = w_b[t]; }
  if (tid < 64) { gb[0][tid] = gamma[tid]; gb[1][tid] = beta[tid]; }
  __syncthreads();

  const int q = tid & 3, sl = tid >> 2;
  const int s = blockIdx.x * 64 + sl;
  const int i = blockIdx.y;
  const float* row = msa + ((size_t)s * I_DIM + i) * CMSA + q * 16;

  float x[16];
  #pragma unroll
  for (int u = 0; u < 4; ++u) {
    float4 v = *(const float4*)(row + 4*u);
    x[4*u] = v.x; x[4*u+1] = v.y; x[4*u+2] = v.z; x[4*u+3] = v.w;
  }
  float sum = 0.f, sq = 0.f;
  #pragma unroll
  for (int j = 0; j < 16; ++j) { sum += x[j]; sq += x[j]*x[j]; }
  sum += __shfl_xor(sum, 1); sum += __shfl_xor(sum, 2);
  sq  += __shfl_xor(sq, 1);  sq  += __shfl_xor(sq, 2);
  const float mean = sum * (1.f/64.f);
  const float var  = sq  * (1.f/64.f) - mean*mean;
  const float rstd = rsqrtf(var + 1e-5f);
  float m[16];
  #pragma unroll
  for (int j = 0; j < 16; ++j)
    m[j] = (x[j] - mean) * rstd * gb[0][q*16+j] + gb[1][q*16+j];

  for (int c = 0; c < 32; ++c) {
    float pa = 0.f, pb = 0.f;
    #pragma unroll
    for (int u = 0; u < 4; ++u) {
      float4 wa = *(const float4*)&wl[0][c][q*16 + 4*u];
      float4 wb = *(const float4*)&wl[1][c][q*16 + 4*u];
      pa += m[4*u]*wa.x + m[4*u+1]*wa.y + m[4*u+2]*wa.z + m[4*u+3]*wa.w;
      pb += m[4*u]*wb.x + m[4*u+1]*wb.y + m[4*u+2]*wb.z + m[4*u+3]*wb.w;
    }
    pa += __shfl_xor(pa, 1); pa += __shfl_xor(pa, 2);
    pb += __shfl_xor(pb, 1); pb += __shfl_xor(pb, 2);
    if (q == 0) {
      atr[0][c][sl] = f2bf(pa * (1.f/512.f));
      atr[1][c][sl] = f2bf(pb);
    }
  }
  __syncthreads();
  const int c2 = tid >> 3, su = (tid & 7) * 8;
  const size_t gbase = ((size_t)i * CDIM + c2) * S_DIM + (size_t)blockIdx.x * 64 + su;
  *(s16x8*)(Ag + gbase) = *(const s16x8*)&atr[0][c2][su];
  *(s16x8*)(Bg + gbase) = *(const s16x8*)&atr[1][c2][su];
}

// ---------------------------------------------------------------------------
// Kernel 2: w_out fp32 -> bf16 with k-permutation: Wp[p][d*32+c] = w[p][c*32+d]
// (matches the epilogue's O_lT layout k' = d*32 + c).
// ---------------------------------------------------------------------------
__global__ __launch_bounds__(256) void wconv_kernel(
    const float* __restrict__ w, unsigned short* __restrict__ wp)
{
  const int idx = blockIdx.x * 256 + threadIdx.x;   // 131072 total
  const int p = idx >> 10, k = idx & 1023;
  const int c = k >> 5, d = k & 31;
  wp[p*1024 + d*32 + c] = f2bf(w[idx]);
}

// ---------------------------------------------------------------------------
// Kernel 3: fused GEMM, 256x256 tile, 8 waves (2M x 4N), BK=64, LDS dbuf.
//   main:  o_tile(256x256, K=512)  [8 kt, stage-early + single barrier]
//   epi A: acc -> O_lT[64 pairs][1024 k'] bf16 in LDS (dual XOR swizzle)
//   epi B: z[128p][64pairs] = Wp(128x1024) @ O_lT^T
// ---------------------------------------------------------------------------
__global__ __launch_bounds__(512, 2) void opm_gemm_kernel(
    const unsigned short* __restrict__ Ag, const unsigned short* __restrict__ Bg,
    const unsigned short* __restrict__ Wp, const float* __restrict__ b_out,
    float* __restrict__ z)
{
  __shared__ __align__(16) unsigned char lds[131072];  // A dbuf 64K | B dbuf 64K; reused as O_lT

  const int tid = threadIdx.x;
  const int l = tid & 63, w = tid >> 6;
  const int wr = w >> 2, wc = w & 3;          // 2M x 4N wave grid

  // T1: bijective XCD swizzle, bm-inner (A panel stays L2-hot per XCD)
  const int bid = blockIdx.x;                 // 0..2303 (2304 % 8 == 0)
  const int xcd = bid & 7, local = bid >> 3;  // local 0..287
  const int bn = local / 6;
  const int bm = xcd * 6 + (local % 6);

  // ---- staging precompute: 4x16B units per thread per matrix ----
  const unsigned short* pA[4];
  const unsigned short* pB[4];
  int u16[4];
  #pragma unroll
  for (int it = 0; it < 4; ++it) {
    const int u = it*512 + tid;               // 0..2047
    const int r = u >> 3, slot = u & 7;
    const int ks8 = slot ^ (r & 7);           // inverse swizzle on global source
    pA[it] = Ag + ((size_t)(bm*256 + r))*S_DIM + ks8*8;
    pB[it] = Bg + ((size_t)(bn*256 + r))*S_DIM + ks8*8;
    u16[it] = u * 16;
  }

  // ---- ds_read base addrs (byte, within buffer, ks=0) ----
  int a_base[8], b_base[4];
  #pragma unroll
  for (int mi = 0; mi < 8; ++mi) {
    const int rowA = wr*128 + mi*16 + (l & 15);
    a_base[mi] = rowA*128 + ((((l >> 4)) ^ (rowA & 7)) << 4);
  }
  #pragma unroll
  for (int ni = 0; ni < 4; ++ni) {
    const int rowB = wc*64 + ni*16 + (l & 15);
    b_base[ni] = 65536 + rowB*128 + ((((l >> 4)) ^ (rowB & 7)) << 4);
  }

  f32x4 acc[8][4];
  #pragma unroll
  for (int a = 0; a < 8; ++a)
    #pragma unroll
    for (int b = 0; b < 4; ++b)
      acc[a][b] = (f32x4){0.f, 0.f, 0.f, 0.f};

  // ---- prologue: stage kt=0 into buf 0 ----
  #pragma unroll
  for (int it = 0; it < 4; ++it) {
    gload_lds16(pA[it], lds + u16[it]);
    gload_lds16(pB[it], lds + 65536 + u16[it]);
    pA[it] += 64; pB[it] += 64;
  }
  __syncthreads();

  int cur = 0;
  for (int kt = 0; kt < 8; ++kt) {
    // issue next-tile staging FIRST (latency hides under compute)
    if (kt < 7) {
      const int nb = (cur ^ 1) * 32768;
      #pragma unroll
      for (int it = 0; it < 4; ++it) {
        gload_lds16(pA[it], lds + nb + u16[it]);
        gload_lds16(pB[it], lds + 65536 + nb + u16[it]);
        pA[it] += 64; pB[it] += 64;
      }
    }
    const int cb = cur * 32768;
    #pragma unroll
    for (int ks = 0; ks < 2; ++ks) {
      bf16x8 af[8], bf[4];
      const int kx = ks << 6;
      #pragma unroll
      for (int mi = 0; mi < 8; ++mi)
        af[mi] = *(const bf16x8*)(lds + cb + (a_base[mi] ^ kx));
      #pragma unroll
      for (int ni = 0; ni < 4; ++ni)
        bf[ni] = *(const bf16x8*)(lds + cb + (b_base[ni] ^ kx));
      __builtin_amdgcn_s_setprio(1);
      #pragma unroll
      for (int mi = 0; mi < 8; ++mi)
        #pragma unroll
        for (int ni = 0; ni < 4; ++ni)
          acc[mi][ni] = __builtin_amdgcn_mfma_f32_16x16x32_bf16(
              af[mi], bf[ni], acc[mi][ni], 0, 0, 0);
      __builtin_amdgcn_s_setprio(0);
    }
    __syncthreads();   // drains vmcnt: staging was issued a full phase ago
    cur ^= 1;
  }

  // ---- epilogue A: acc -> O_lT[pair][k'=d*32+c], bf16, dual XOR swizzle ----
  #pragma unroll
  for (int mi = 0; mi < 8; ++mi) {
    const int iloc = wr*4 + (mi >> 1);
    const int cb2 = (mi & 1)*16 + (l >> 4)*4;
    #pragma unroll
    for (int ni = 0; ni < 4; ++ni) {
      const int jloc = wc*2 + (ni >> 1);
      const int d = (ni & 1)*16 + (l & 15);
      const int pair = iloc*8 + jloc;
      #pragma unroll
      for (int rp = 0; rp < 2; ++rp) {
        const int kp = d*32 + cb2 + 2*rp;              // even
        int byte = pair*2048 + kp*2;
        byte ^= ((pair & 7) << 4) ^ (((byte >> 7) & 7) << 4);
        unsigned int val = (unsigned int)f2bf(acc[mi][ni][2*rp])
                         | ((unsigned int)f2bf(acc[mi][ni][2*rp+1]) << 16);
        *(unsigned int*)(lds + byte) = val;
      }
    }
  }
  __syncthreads();

  // ---- epilogue B: z = Wp @ O_lT^T ; wave w owns p-rows [w*16, w*16+16) ----
  const unsigned short* wrow = Wp + ((size_t)(w*16 + (l & 15)))*1024 + (l >> 4)*8;
  f32x4 accz[4];
  #pragma unroll
  for (int ni = 0; ni < 4; ++ni) accz[ni] = (f32x4){0.f,0.f,0.f,0.f};

  #pragma unroll 4
  for (int ksp = 0; ksp < 32; ++ksp) {
    const bf16x8 wf = *(const bf16x8*)(wrow + ksp*32);
    const int kbyte = ksp*64 + (l >> 4)*16;
    const int kswz = ((kbyte >> 7) & 7) << 4;
    #pragma unroll
    for (int ni = 0; ni < 4; ++ni) {
      const int pair = ni*16 + (l & 15);
      int byte = pair*2048 + kbyte;
      byte ^= ((pair & 7) << 4) ^ kswz;
      const bf16x8 of = *(const bf16x8*)(lds + byte);
      accz[ni] = __builtin_amdgcn_mfma_f32_16x16x32_bf16(wf, of, accz[ni], 0, 0, 0);
    }
  }

  // ---- store z + b_out (float4 over consecutive p) ----
  const int p0 = w*16 + (l >> 4)*4;
  const float4 bo = *(const float4*)(b_out + p0);
  #pragma unroll
  for (int ni = 0; ni < 4; ++ni) {
    const int pair = ni*16 + (l & 15);
    const int gi = bm*8 + (pair >> 3), gj = bn*8 + (pair & 7);
    float4 v;
    v.x = accz[ni][0] + bo.x; v.y = accz[ni][1] + bo.y;
    v.z = accz[ni][2] + bo.z; v.w = accz[ni][3] + bo.w;
    *(float4*)(z + ((size_t)gi * I_DIM + gj) * P_DIM + p0) = v;
  }
}

extern "C" void kernel_launch(void* const* d_in, const int* in_sizes, int n_in,
                              void* d_out, int out_size, void* d_ws, size_t ws_size,
                              hipStream_t stream) {
  const float* msa   = (const float*)d_in[0];
  const float* gamma = (const float*)d_in[1];
  const float* beta  = (const float*)d_in[2];
  const float* w_a   = (const float*)d_in[3];
  const float* w_b   = (const float*)d_in[4];
  const float* w_out = (const float*)d_in[5];
  const float* b_out = (const float*)d_in[6];
  float* z = (float*)d_out;

  unsigned short* Ag = (unsigned short*)d_ws;                 // 12.6 MB
  unsigned short* Bg = Ag + (size_t)M_DIM * S_DIM;            // 12.6 MB
  unsigned short* Wp = Bg + (size_t)M_DIM * S_DIM;            // 256 KB

  hipLaunchKernelGGL(ln_proj_kernel, dim3(8, 384), dim3(256), 0, stream,
                     msa, gamma, beta, w_a, w_b, Ag, Bg);
  hipLaunchKernelGGL(wconv_kernel, dim3(512), dim3(256), 0, stream, w_out, Wp);
  hipLaunchKernelGGL(opm_gemm_kernel, dim3(2304), dim3(512), 0, stream,
                     Ag, Bg, Wp, b_out, z);
}